// Round 14
// baseline (199.044 us; speedup 1.0000x reference)
//
#include <hip/hip_runtime.h>

#define NN 10000
#define NE 320000
#define ROW_WORDS 320   // 320*32 = 10240 bits >= 10000
#define MP 10112        // 158*64 padded rows
#define BN_EPS 1e-5f

typedef __attribute__((ext_vector_type(8))) short short8;
typedef __attribute__((ext_vector_type(4))) float f32x4;
typedef unsigned short u16;

// ---------------- helpers ----------------
__device__ __forceinline__ void split1(float v, u16& h, u16& l) {
    unsigned int u = __float_as_uint(v);
    h = (u16)(u >> 16);
    float hf = __uint_as_float(u & 0xFFFF0000u);
    l = (u16)(__float_as_uint(v - hf) >> 16);
}

__device__ __forceinline__ void gll16(const void* g, void* l) {
    __builtin_amdgcn_global_load_lds(
        (const __attribute__((address_space(1))) unsigned int*)g,
        (__attribute__((address_space(3))) unsigned int*)l, 16, 0, 0);
}

// ---------------- scatter: dedup bitmap ----------------
__global__ void scatter_bits(const int* __restrict__ ei, unsigned int* __restrict__ bitmap) {
    int t = blockIdx.x * blockDim.x + threadIdx.x;
    if (t < NE) {
        int i = ei[t];
        int j = ei[NE + t];
        atomicOr(&bitmap[i * ROW_WORDS + (j >> 5)], 1u << (j & 31));
    } else if (t < NE + NN) {
        int i = t - NE;
        atomicOr(&bitmap[i * ROW_WORDS + (i >> 5)], 1u << (i & 31));
    }
}

// ---------------- prep device fns (proven round 8/11) ----------------
__device__ void splitW_dev(const float* __restrict__ W, int K, int N, int Kp, int Np,
                           u16* __restrict__ Wt, int bx, int by, char* smem) {
    float (*tile)[65] = (float(*)[65])smem;
    int t = threadIdx.x;
    int bk = bx * 64, bn = by * 64;
    #pragma unroll
    for (int p = 0; p < 4; ++p) {
        int kk = (t >> 4) + p * 16;
        int nc = (t & 15) * 4;
        int k = bk + kk;
        float4 v = {0.f, 0.f, 0.f, 0.f};
        if (k < K && bn + nc + 3 < N)
            v = *(const float4*)&W[(size_t)k * N + bn + nc];
        tile[kk][nc] = v.x; tile[kk][nc + 1] = v.y;
        tile[kk][nc + 2] = v.z; tile[kk][nc + 3] = v.w;
    }
    __syncthreads();
    int nn = t >> 2;
    int kk0 = (t & 3) * 16;
    u16 hs[16], ls[16];
    #pragma unroll
    for (int j = 0; j < 16; ++j) split1(tile[kk0 + j][nn], hs[j], ls[j]);
    size_t ob = (size_t)(bn + nn) * Kp + bk + kk0;
    size_t lo = (size_t)Np * Kp;
    *(short8*)&Wt[ob] = *(short8*)hs;
    *(short8*)&Wt[ob + 8] = *(short8*)&hs[8];
    *(short8*)&Wt[lo + ob] = *(short8*)ls;
    *(short8*)&Wt[lo + ob + 8] = *(short8*)&ls[8];
}

__device__ void xsplit_dev(const float* __restrict__ x, u16* __restrict__ xs, int gblk) {
    int t = threadIdx.x;
    int r0 = gblk * 16 + (t >> 4);
    int l = t & 15;
    u16* xlo = xs + (size_t)MP * 512;
    #pragma unroll
    for (int j = 0; j < 8; ++j) {
        int k = (l + j * 16) * 4;
        float vals[4] = {0.f, 0.f, 0.f, 0.f};
        if (r0 < NN && k < 500) {
            float4 v = *(const float4*)&x[(size_t)r0 * 500 + k];
            vals[0] = v.x; vals[1] = v.y; vals[2] = v.z; vals[3] = v.w;
        }
        ushort4 hs, ls;
        split1(vals[0], hs.x, ls.x); split1(vals[1], hs.y, ls.y);
        split1(vals[2], hs.z, ls.z); split1(vals[3], hs.w, ls.w);
        *(ushort4*)&xs[(size_t)r0 * 512 + k] = hs;
        *(ushort4*)&xlo[(size_t)r0 * 512 + k] = ls;
    }
}

__device__ void degree_dev(const unsigned int* __restrict__ bitmap, float* __restrict__ deg,
                           int gblk) {
    int t = threadIdx.x;
    int r = gblk * 16 + (t >> 4), l = t & 15;
    int cnt = 0;
    if (r < NN)
        for (int wd = l; wd < ROW_WORDS; wd += 16)
            cnt += __popc(bitmap[(size_t)r * ROW_WORDS + wd]);
    cnt += __shfl_down(cnt, 8, 16);
    cnt += __shfl_down(cnt, 4, 16);
    cnt += __shfl_down(cnt, 2, 16);
    cnt += __shfl_down(cnt, 1, 16);
    if (l == 0 && r < NN) deg[r] = (float)cnt;
}

// ---------------- prep: degree + split x + split W0 + split fW1 (r11 form) ------
__global__ __launch_bounds__(256)
void prep(const unsigned int* __restrict__ bitmap, const float* __restrict__ x,
          const float* __restrict__ W0, const float* __restrict__ fW1,
          float* __restrict__ deg, u16* __restrict__ xs,
          u16* __restrict__ W0t, u16* __restrict__ fW1t) {
    __shared__ char smem[16704];
    int b = blockIdx.x;
    if (b < 632) {
        degree_dev(bitmap, deg, b);
        xsplit_dev(x, xs, b);
    } else if (b < 664) {
        int idx = b - 632;
        splitW_dev(W0, 500, 256, 512, 256, W0t, idx & 7, idx >> 3, smem);
    } else {
        splitW_dev(fW1, 128, 40, 128, 64, fW1t, b - 664, 0, smem);
    }
}

// ---------------- conv0 GEMM: BM=64, BN=128 (halves A-fetch duplication) --------
// grid 320 flat; xcd=b&7, g=b>>3: bx=g&1, by=(g>>1)*8+xcd. occ 3, 48 KB LDS.
__global__ __launch_bounds__(256, 3)
void conv0_gemm(const u16* __restrict__ Ahi, const u16* __restrict__ Alo,
                const u16* __restrict__ Bhi, const u16* __restrict__ Blo,
                const float* __restrict__ bias, const float* __restrict__ deg,
                float* __restrict__ stats, u16* __restrict__ Ohi, u16* __restrict__ Olo) {
    __shared__ char smem[49152];   // Ahi 8K | Alo 8K | Bhi 16K | Blo 16K
    const int Kp = 512, M = NN, No = 256;
    const int b = blockIdx.x;
    const int xcd = b & 7, g = b >> 3;
    const int bx = g & 1, by = (g >> 1) * 8 + xcd;
    if (by >= 158) return;
    const int t = threadIdx.x;
    const int lane = t & 63;
    const int w = t >> 6;
    const int q = lane >> 4;
    const int l16 = lane & 15;
    const int m7 = l16 & 7;
    const int row0 = by * 64;
    const int col0 = bx * 128;

    // A: 16 wave-loads (hi 8 | lo 8), 4/wave
    const u16* asp[4];
    unsigned adst[4];
    #pragma unroll
    for (int i = 0; i < 4; ++i) {
        int gi = w + i * 4;
        int plane = gi >> 3, j = gi & 7;
        int r = j * 8 + (lane >> 3);
        int c = (lane & 7) ^ (r & 7);
        asp[i] = (plane ? Alo : Ahi) + (size_t)(row0 + r) * Kp + c * 8;
        adst[i] = plane * 8192 + j * 1024;
    }
    // B: 32 wave-loads (hi 16 | lo 16), 8/wave
    const u16* bsp[8];
    unsigned bdst[8];
    #pragma unroll
    for (int i = 0; i < 8; ++i) {
        int gi = w + i * 4;
        int plane = gi >> 4, j = gi & 15;
        int r = j * 8 + (lane >> 3);
        int c = (lane & 7) ^ (r & 7);
        bsp[i] = (plane ? Blo : Bhi) + (size_t)(col0 + r) * Kp + c * 8;
        bdst[i] = 16384 + plane * 16384 + j * 1024;
    }

    f32x4 acc[8];
    #pragma unroll
    for (int s = 0; s < 8; ++s) acc[s] = (f32x4){0.f, 0.f, 0.f, 0.f};

    #pragma unroll
    for (int i = 0; i < 4; ++i) { gll16(asp[i], smem + adst[i]); asp[i] += 64; }
    #pragma unroll
    for (int i = 0; i < 8; ++i) { gll16(bsp[i], smem + bdst[i]); bsp[i] += 64; }

    for (int k0 = 0; k0 < Kp; k0 += 64) {
        __syncthreads();   // (1) tile resident
        short8 ah[2], al[2], bh[2][8], bl[2][8];
        #pragma unroll
        for (int kc = 0; kc < 2; ++kc) {
            int aoff = (w * 16 + l16) * 128 + (((kc * 4 + q) ^ m7) * 16);
            ah[kc] = *(const short8*)(smem + aoff);
            al[kc] = *(const short8*)(smem + 8192 + aoff);
            #pragma unroll
            for (int s = 0; s < 8; ++s) {
                int boff = (s * 16 + l16) * 128 + (((kc * 4 + q) ^ m7) * 16);
                bh[kc][s] = *(const short8*)(smem + 16384 + boff);
                bl[kc][s] = *(const short8*)(smem + 32768 + boff);
            }
        }
        __syncthreads();   // (2) all reads done
        if (k0 + 64 < Kp) {
            #pragma unroll
            for (int i = 0; i < 4; ++i) { gll16(asp[i], smem + adst[i]); asp[i] += 64; }
            #pragma unroll
            for (int i = 0; i < 8; ++i) { gll16(bsp[i], smem + bdst[i]); bsp[i] += 64; }
        }
        #pragma unroll
        for (int kc = 0; kc < 2; ++kc)
            #pragma unroll
            for (int s = 0; s < 8; ++s) {
                acc[s] = __builtin_amdgcn_mfma_f32_16x16x32_bf16(al[kc], bh[kc][s], acc[s], 0, 0, 0);
                acc[s] = __builtin_amdgcn_mfma_f32_16x16x32_bf16(ah[kc], bl[kc][s], acc[s], 0, 0, 0);
                acc[s] = __builtin_amdgcn_mfma_f32_16x16x32_bf16(ah[kc], bh[kc][s], acc[s], 0, 0, 0);
            }
    }

    int growb = row0 + w * 16 + q * 4;
    float dgv[4];
    #pragma unroll
    for (int r = 0; r < 4; ++r) dgv[r] = (growb + r < M) ? deg[growb + r] : 0.f;
    #pragma unroll
    for (int s = 0; s < 8; ++s) {
        int gc = col0 + s * 16 + l16;
        float bia = bias[gc];
        float s_sum = 0.f, ss_sum = 0.f;
        #pragma unroll
        for (int r = 0; r < 4; ++r) {
            int grow = growb + r;
            bool real = grow < M;
            float v = fmaxf(fmaf(dgv[r], acc[s][r], bia), 0.f);
            if (!real) v = 0.f;
            s_sum += v; ss_sum += v * v;
            float vo = v * dgv[r];
            u16 h, l; split1(vo, h, l);
            Ohi[(size_t)grow * No + gc] = h;
            Olo[(size_t)grow * No + gc] = l;
        }
        s_sum  += __shfl_xor(s_sum, 16);  s_sum  += __shfl_xor(s_sum, 32);
        ss_sum += __shfl_xor(ss_sum, 16); ss_sum += __shfl_xor(ss_sum, 32);
        if (lane < 16) {
            atomicAdd(&stats[gc], s_sum);
            atomicAdd(&stats[256 + gc], ss_sum);
        }
    }
}

// ---------------- conv1 with in-kernel BN0 fold of W1 (proven r11) ----------------
__global__ __launch_bounds__(256, 4)
void conv1_fold(const u16* __restrict__ Ahi, const u16* __restrict__ Alo,
                const float* __restrict__ W1, const float* __restrict__ stats0,
                const float* __restrict__ g0, const float* __restrict__ bb0,
                const float* __restrict__ b1, const float* __restrict__ deg,
                float* __restrict__ stats1, u16* __restrict__ Ohi, u16* __restrict__ Olo) {
    __shared__ char smem[32768];
    __shared__ float scl[256], sh[256], cred[256], cvec[64];
    const int Kp = 256, M = NN, No = 256;
    const int b = blockIdx.x;
    const int xcd = b & 7, g = b >> 3;
    const int bx = g & 3, by = (g >> 2) * 8 + xcd;
    if (by >= 158) return;
    const int t = threadIdx.x;
    const int lane = t & 63;
    const int w = t >> 6;
    const int q = lane >> 4;
    const int l16 = lane & 15;
    const int m7 = l16 & 7;
    const int row0 = by * 64;
    const int col0 = bx * 64;

    const u16* srcs[4];
    unsigned dstoff[4];
    #pragma unroll
    for (int i = 0; i < 4; ++i) {
        int gi = w + i * 4;
        int plane = gi >> 3, j = gi & 7;
        int r = j * 8 + (lane >> 3);
        int c = (lane & 7) ^ (r & 7);
        srcs[i] = (plane ? Alo : Ahi) + (size_t)(row0 + r) * Kp + c * 8;
        dstoff[i] = plane * 8192 + j * 1024;
    }
    #pragma unroll
    for (int i = 0; i < 4; ++i) { gll16(srcs[i], smem + dstoff[i]); srcs[i] += 64; }

    {
        float mean = stats0[t] * (1.f / NN);
        float var = stats0[256 + t] * (1.f / NN) - mean * mean;
        float s = g0[t] * rsqrtf(var + BN_EPS);
        scl[t] = s;
        sh[t] = bb0[t] - mean * s;
    }
    __syncthreads();
    {
        float s = 0.f;
        int n = col0 + (t & 63);
        #pragma unroll 8
        for (int k = (t >> 6); k < 256; k += 4)
            s += sh[k] * W1[(size_t)k * 256 + n];
        cred[t] = s;
        __syncthreads();
        if (t < 64) cvec[t] = cred[t] + cred[t + 64] + cred[t + 128] + cred[t + 192];
    }
    const int bn = t & 63;
    const int kb = (t >> 6) * 16;
    const int ch0 = (t >> 6) * 2;
    float vals[16];
    {
        const float* wp = W1 + (size_t)kb * 256 + col0 + bn;
        #pragma unroll
        for (int i = 0; i < 16; ++i) vals[i] = wp[(size_t)i * 256] * scl[kb + i];
    }

    f32x4 acc[4];
    #pragma unroll
    for (int s = 0; s < 4; ++s) acc[s] = (f32x4){0.f, 0.f, 0.f, 0.f};

    for (int k0 = 0; k0 < Kp; k0 += 64) {
        {
            u16 hs[16], ls[16];
            #pragma unroll
            for (int i = 0; i < 16; ++i) split1(vals[i], hs[i], ls[i]);
            unsigned o0 = bn * 128 + ((ch0 ^ (bn & 7)) * 16);
            unsigned o1 = bn * 128 + (((ch0 + 1) ^ (bn & 7)) * 16);
            *(short8*)(smem + 16384 + o0) = *(short8*)&hs[0];
            *(short8*)(smem + 16384 + o1) = *(short8*)&hs[8];
            *(short8*)(smem + 24576 + o0) = *(short8*)&ls[0];
            *(short8*)(smem + 24576 + o1) = *(short8*)&ls[8];
        }
        __syncthreads();   // (1)
        short8 ah[2], al[2], bh[2][4], bl[2][4];
        #pragma unroll
        for (int kc = 0; kc < 2; ++kc) {
            int aoff = (w * 16 + l16) * 128 + (((kc * 4 + q) ^ m7) * 16);
            ah[kc] = *(const short8*)(smem + aoff);
            al[kc] = *(const short8*)(smem + 8192 + aoff);
            #pragma unroll
            for (int s = 0; s < 4; ++s) {
                int boff = (s * 16 + l16) * 128 + (((kc * 4 + q) ^ m7) * 16);
                bh[kc][s] = *(const short8*)(smem + 16384 + boff);
                bl[kc][s] = *(const short8*)(smem + 24576 + boff);
            }
        }
        __syncthreads();   // (2)
        if (k0 + 64 < Kp) {
            #pragma unroll
            for (int i = 0; i < 4; ++i) { gll16(srcs[i], smem + dstoff[i]); srcs[i] += 64; }
            const float* wp = W1 + (size_t)(k0 + 64 + kb) * 256 + col0 + bn;
            #pragma unroll
            for (int i = 0; i < 16; ++i) vals[i] = wp[(size_t)i * 256] * scl[k0 + 64 + kb + i];
        }
        #pragma unroll
        for (int kc = 0; kc < 2; ++kc)
            #pragma unroll
            for (int s = 0; s < 4; ++s) {
                acc[s] = __builtin_amdgcn_mfma_f32_16x16x32_bf16(al[kc], bh[kc][s], acc[s], 0, 0, 0);
                acc[s] = __builtin_amdgcn_mfma_f32_16x16x32_bf16(ah[kc], bl[kc][s], acc[s], 0, 0, 0);
                acc[s] = __builtin_amdgcn_mfma_f32_16x16x32_bf16(ah[kc], bh[kc][s], acc[s], 0, 0, 0);
            }
    }

    int growb = row0 + w * 16 + q * 4;
    float dgv[4];
    #pragma unroll
    for (int r = 0; r < 4; ++r) dgv[r] = (growb + r < M) ? deg[growb + r] : 0.f;
    #pragma unroll
    for (int s = 0; s < 4; ++s) {
        int gc = col0 + s * 16 + l16;
        float bia = b1[gc];
        float cv = cvec[s * 16 + l16];
        float s_sum = 0.f, ss_sum = 0.f;
        #pragma unroll
        for (int r = 0; r < 4; ++r) {
            int grow = growb + r;
            bool real = grow < M;
            float v = fmaxf(fmaf(dgv[r], cv, acc[s][r] + bia), 0.f);
            if (!real) v = 0.f;
            s_sum += v; ss_sum += v * v;
            u16 h, l; split1(v, h, l);
            Ohi[(size_t)grow * No + gc] = h;
            Olo[(size_t)grow * No + gc] = l;
        }
        s_sum  += __shfl_xor(s_sum, 16);  s_sum  += __shfl_xor(s_sum, 32);
        ss_sum += __shfl_xor(ss_sum, 16); ss_sum += __shfl_xor(ss_sum, 32);
        if (lane < 16) {
            atomicAdd(&stats1[gc], s_sum);
            atomicAdd(&stats1[256 + gc], ss_sum);
        }
    }
}

// ---------------- fc0 with in-kernel BN1 fold of fW0 (proven r11) ----------------
__global__ __launch_bounds__(256, 4)
void fc0_fold(const u16* __restrict__ Ahi, const u16* __restrict__ Alo,
              const float* __restrict__ fW0, const float* __restrict__ stats1,
              const float* __restrict__ g1, const float* __restrict__ bb1,
              const float* __restrict__ fb0,
              u16* __restrict__ Ohi, u16* __restrict__ Olo) {
    __shared__ char smem[32768];
    __shared__ float scl[256], sh[256], cred[256], biasf[64];
    const int Kp = 256, M = NN, No = 128;
    const int b = blockIdx.x;
    const int xcd = b & 7, g = b >> 3;
    const int bx = g & 1, by = (g >> 1) * 8 + xcd;
    if (by >= 158) return;
    const int t = threadIdx.x;
    const int lane = t & 63;
    const int w = t >> 6;
    const int q = lane >> 4;
    const int l16 = lane & 15;
    const int m7 = l16 & 7;
    const int row0 = by * 64;
    const int col0 = bx * 64;

    const u16* srcs[4];
    unsigned dstoff[4];
    #pragma unroll
    for (int i = 0; i < 4; ++i) {
        int gi = w + i * 4;
        int plane = gi >> 3, j = gi & 7;
        int r = j * 8 + (lane >> 3);
        int c = (lane & 7) ^ (r & 7);
        srcs[i] = (plane ? Alo : Ahi) + (size_t)(row0 + r) * Kp + c * 8;
        dstoff[i] = plane * 8192 + j * 1024;
    }
    #pragma unroll
    for (int i = 0; i < 4; ++i) { gll16(srcs[i], smem + dstoff[i]); srcs[i] += 64; }

    {
        float mean = stats1[t] * (1.f / NN);
        float var = stats1[256 + t] * (1.f / NN) - mean * mean;
        float s = g1[t] * rsqrtf(var + BN_EPS);
        scl[t] = s;
        sh[t] = bb1[t] - mean * s;
    }
    __syncthreads();
    {
        float s = 0.f;
        int n = col0 + (t & 63);
        #pragma unroll 8
        for (int k = (t >> 6); k < 256; k += 4)
            s += sh[k] * fW0[(size_t)k * 128 + n];
        cred[t] = s;
        __syncthreads();
        if (t < 64)
            biasf[t] = fb0[col0 + t] + cred[t] + cred[t + 64] + cred[t + 128] + cred[t + 192];
    }
    const int bn = t & 63;
    const int kb = (t >> 6) * 16;
    const int ch0 = (t >> 6) * 2;
    float vals[16];
    {
        const float* wp = fW0 + (size_t)kb * 128 + col0 + bn;
        #pragma unroll
        for (int i = 0; i < 16; ++i) vals[i] = wp[(size_t)i * 128] * scl[kb + i];
    }

    f32x4 acc[4];
    #pragma unroll
    for (int s = 0; s < 4; ++s) acc[s] = (f32x4){0.f, 0.f, 0.f, 0.f};

    for (int k0 = 0; k0 < Kp; k0 += 64) {
        {
            u16 hs[16], ls[16];
            #pragma unroll
            for (int i = 0; i < 16; ++i) split1(vals[i], hs[i], ls[i]);
            unsigned o0 = bn * 128 + ((ch0 ^ (bn & 7)) * 16);
            unsigned o1 = bn * 128 + (((ch0 + 1) ^ (bn & 7)) * 16);
            *(short8*)(smem + 16384 + o0) = *(short8*)&hs[0];
            *(short8*)(smem + 16384 + o1) = *(short8*)&hs[8];
            *(short8*)(smem + 24576 + o0) = *(short8*)&ls[0];
            *(short8*)(smem + 24576 + o1) = *(short8*)&ls[8];
        }
        __syncthreads();   // (1)
        short8 ah[2], al[2], bh[2][4], bl[2][4];
        #pragma unroll
        for (int kc = 0; kc < 2; ++kc) {
            int aoff = (w * 16 + l16) * 128 + (((kc * 4 + q) ^ m7) * 16);
            ah[kc] = *(const short8*)(smem + aoff);
            al[kc] = *(const short8*)(smem + 8192 + aoff);
            #pragma unroll
            for (int s = 0; s < 4; ++s) {
                int boff = (s * 16 + l16) * 128 + (((kc * 4 + q) ^ m7) * 16);
                bh[kc][s] = *(const short8*)(smem + 16384 + boff);
                bl[kc][s] = *(const short8*)(smem + 24576 + boff);
            }
        }
        __syncthreads();   // (2)
        if (k0 + 64 < Kp) {
            #pragma unroll
            for (int i = 0; i < 4; ++i) { gll16(srcs[i], smem + dstoff[i]); srcs[i] += 64; }
            const float* wp = fW0 + (size_t)(k0 + 64 + kb) * 128 + col0 + bn;
            #pragma unroll
            for (int i = 0; i < 16; ++i) vals[i] = wp[(size_t)i * 128] * scl[k0 + 64 + kb + i];
        }
        #pragma unroll
        for (int kc = 0; kc < 2; ++kc)
            #pragma unroll
            for (int s = 0; s < 4; ++s) {
                acc[s] = __builtin_amdgcn_mfma_f32_16x16x32_bf16(al[kc], bh[kc][s], acc[s], 0, 0, 0);
                acc[s] = __builtin_amdgcn_mfma_f32_16x16x32_bf16(ah[kc], bl[kc][s], acc[s], 0, 0, 0);
                acc[s] = __builtin_amdgcn_mfma_f32_16x16x32_bf16(ah[kc], bh[kc][s], acc[s], 0, 0, 0);
            }
    }

    int growb = row0 + w * 16 + q * 4;
    #pragma unroll
    for (int s = 0; s < 4; ++s) {
        int gc = col0 + s * 16 + l16;
        float bia = biasf[s * 16 + l16];
        #pragma unroll
        for (int r = 0; r < 4; ++r) {
            int grow = growb + r;
            float v = fmaxf(acc[s][r] + bia, 0.f);
            if (grow >= M) v = 0.f;
            u16 h, l; split1(v, h, l);
            Ohi[(size_t)grow * No + gc] = h;
            Olo[(size_t)grow * No + gc] = l;
        }
    }
}

// ---------------- fc1 (proven): Kp=128, N=40, fp32 out ----------------
__global__ __launch_bounds__(256, 3)
void fc1_gemm(const u16* __restrict__ Ahi, const u16* __restrict__ Alo,
              const u16* __restrict__ Bhi, const u16* __restrict__ Blo,
              const float* __restrict__ bias, float* __restrict__ out) {
    __shared__ char smem[32768];
    const int Kp = 128, M = NN, N = 40, No = 40;
    const int t = threadIdx.x;
    const int lane = t & 63;
    const int w = t >> 6;
    const int q = lane >> 4;
    const int l16 = lane & 15;
    const int m7 = l16 & 7;
    const int row0 = blockIdx.x * 64;
    const int col0 = 0;

    const u16* bases[4] = {Ahi, Alo, Bhi, Blo};
    const u16* srcs[8];
    unsigned dstoff[8];
    #pragma unroll
    for (int i = 0; i < 8; ++i) {
        int gi = w + i * 4;
        int reg = i >> 1;
        int j = gi & 7;
        int rb = (reg < 2) ? row0 : col0;
        int r = j * 8 + (lane >> 3);
        int c = (lane & 7) ^ (r & 7);
        srcs[i] = bases[reg] + (size_t)(rb + r) * Kp + c * 8;
        dstoff[i] = reg * 8192 + j * 1024;
    }

    f32x4 acc[4];
    #pragma unroll
    for (int s = 0; s < 4; ++s) acc[s] = (f32x4){0.f, 0.f, 0.f, 0.f};

    #pragma unroll
    for (int i = 0; i < 8; ++i) { gll16(srcs[i], smem + dstoff[i]); srcs[i] += 64; }

    for (int k0 = 0; k0 < Kp; k0 += 64) {
        __syncthreads();
        short8 ah[2], al[2], bh[2][4], bl[2][4];
        #pragma unroll
        for (int kc = 0; kc < 2; ++kc) {
            int aoff = (w * 16 + l16) * 128 + (((kc * 4 + q) ^ m7) * 16);
            ah[kc] = *(const short8*)(smem + aoff);
            al[kc] = *(const short8*)(smem + 8192 + aoff);
            #pragma unroll
            for (int s = 0; s < 4; ++s) {
                int boff = (s * 16 + l16) * 128 + (((kc * 4 + q) ^ m7) * 16);
                bh[kc][s] = *(const short8*)(smem + 16384 + boff);
                bl[kc][s] = *(const short8*)(smem + 24576 + boff);
            }
        }
        __syncthreads();
        if (k0 + 64 < Kp) {
            #pragma unroll
            for (int i = 0; i < 8; ++i) { gll16(srcs[i], smem + dstoff[i]); srcs[i] += 64; }
        }
        #pragma unroll
        for (int kc = 0; kc < 2; ++kc)
            #pragma unroll
            for (int s = 0; s < 4; ++s) {
                acc[s] = __builtin_amdgcn_mfma_f32_16x16x32_bf16(al[kc], bh[kc][s], acc[s], 0, 0, 0);
                acc[s] = __builtin_amdgcn_mfma_f32_16x16x32_bf16(ah[kc], bl[kc][s], acc[s], 0, 0, 0);
                acc[s] = __builtin_amdgcn_mfma_f32_16x16x32_bf16(ah[kc], bh[kc][s], acc[s], 0, 0, 0);
            }
    }

    int growb = row0 + w * 16 + q * 4;
    #pragma unroll
    for (int s = 0; s < 4; ++s) {
        int gc = col0 + s * 16 + l16;
        if (gc >= N) continue;
        float bia = bias[gc];
        #pragma unroll
        for (int r = 0; r < 4; ++r) {
            int grow = growb + r;
            if (grow < M)
                out[(size_t)grow * No + gc] = fmaxf(acc[s][r] + bia, 0.f);
        }
    }
}

// ---------------- launch ----------------

extern "C" void kernel_launch(void* const* d_in, const int* in_sizes, int n_in,
                              void* d_out, int out_size, void* d_ws, size_t ws_size,
                              hipStream_t stream) {
    const float* x   = (const float*)d_in[0];
    const int*   ei  = (const int*)d_in[1];
    const float* W0  = (const float*)d_in[2];
    const float* b0  = (const float*)d_in[3];
    const float* g0  = (const float*)d_in[4];
    const float* bb0 = (const float*)d_in[5];
    const float* W1  = (const float*)d_in[6];
    const float* b1  = (const float*)d_in[7];
    const float* g1  = (const float*)d_in[8];
    const float* bb1 = (const float*)d_in[9];
    const float* fW0 = (const float*)d_in[10];
    const float* fb0 = (const float*)d_in[11];
    const float* fW1 = (const float*)d_in[12];
    const float* fb1 = (const float*)d_in[13];
    float* out = (float*)d_out;

    char* ws = (char*)d_ws;
    auto carve = [&](size_t bytes) { char* q = ws; ws += (bytes + 255) & ~(size_t)255; return q; };

    const size_t BITMAP_BYTES = (size_t)NN * ROW_WORDS * 4;   // 12,800,000
    char* region0 = carve(BITMAP_BYTES + 4096);
    unsigned int* bitmap = (unsigned int*)region0;
    float* stats = (float*)(region0 + BITMAP_BYTES);   // [0,512) conv0, [512,1024) conv1
    u16* H1 = (u16*)region0;                           // hi|lo, reuses bitmap after degree

    float* deg  = (float*)carve(MP * 4);
    u16* xs     = (u16*)carve((size_t)2 * MP * 512 * 2);
    u16* W0t    = (u16*)carve((size_t)2 * 256 * 512 * 2);
    u16* fW1t   = (u16*)carve((size_t)2 * 64 * 128 * 2);
    u16* H2     = (u16*)carve((size_t)2 * MP * 256 * 2);
    u16* H3     = (u16*)carve((size_t)2 * MP * 128 * 2);

    dim3 blk(256);

    // 1. zero bitmap + stats
    hipMemsetAsync(region0, 0, BITMAP_BYTES + 4096, stream);
    // 2. scatter edges
    scatter_bits<<<(NE + NN + 255) / 256, blk, 0, stream>>>(ei, bitmap);
    // 3. degree + split x/W0/fW1 (r11 form)
    prep<<<666, blk, 0, stream>>>(bitmap, x, W0, fW1, deg, xs, W0t, fW1t);
    // 4. conv0 (BN=128 tile: 2 column blocks -> half the A-fetch duplication)
    conv0_gemm<<<320, blk, 0, stream>>>(
        xs, xs + (size_t)MP * 512, W0t, W0t + 256 * 512,
        b0, deg, stats, H1, H1 + (size_t)MP * 256);
    // 5. conv1 (self-folds BN0 into W1; swizzled)
    conv1_fold<<<640, blk, 0, stream>>>(
        H1, H1 + (size_t)MP * 256, W1, stats, g0, bb0, b1, deg,
        stats + 512, H2, H2 + (size_t)MP * 256);
    // 6. fc0 (self-folds BN1 into fW0; swizzled)
    fc0_fold<<<320, blk, 0, stream>>>(
        H2, H2 + (size_t)MP * 256, fW0, stats + 512, g1, bb1, fb0,
        H3, H3 + (size_t)MP * 128);
    // 7. fc1
    fc1_gemm<<<158, blk, 0, stream>>>(
        H3, H3 + (size_t)MP * 128, fW1t, fW1t + 64 * 128, fb1, out);
}

// Round 15
// 185.151 us; speedup vs baseline: 1.0750x; 1.0750x over previous
//
#include <hip/hip_runtime.h>

#define NN 10000
#define NE 320000
#define ROW_WORDS 320   // 320*32 = 10240 bits >= 10000
#define MP 10112        // 158*64 padded rows
#define BN_EPS 1e-5f

typedef __attribute__((ext_vector_type(8))) short short8;
typedef __attribute__((ext_vector_type(4))) float f32x4;
typedef unsigned short u16;

// ---------------- helpers ----------------
__device__ __forceinline__ void split1(float v, u16& h, u16& l) {
    unsigned int u = __float_as_uint(v);
    h = (u16)(u >> 16);
    float hf = __uint_as_float(u & 0xFFFF0000u);
    l = (u16)(__float_as_uint(v - hf) >> 16);
}

__device__ __forceinline__ void gll16(const void* g, void* l) {
    __builtin_amdgcn_global_load_lds(
        (const __attribute__((address_space(1))) unsigned int*)g,
        (__attribute__((address_space(3))) unsigned int*)l, 16, 0, 0);
}

// ---------------- splitW (proven): Wt[n][k] = split(W[k][n]) ----------------
__device__ void splitW_dev(const float* __restrict__ W, int K, int N, int Kp, int Np,
                           u16* __restrict__ Wt, int bx, int by, char* smem) {
    float (*tile)[65] = (float(*)[65])smem;
    int t = threadIdx.x;
    int bk = bx * 64, bn = by * 64;
    #pragma unroll
    for (int p = 0; p < 4; ++p) {
        int kk = (t >> 4) + p * 16;
        int nc = (t & 15) * 4;
        int k = bk + kk;
        float4 v = {0.f, 0.f, 0.f, 0.f};
        if (k < K && bn + nc + 3 < N)
            v = *(const float4*)&W[(size_t)k * N + bn + nc];
        tile[kk][nc] = v.x; tile[kk][nc + 1] = v.y;
        tile[kk][nc + 2] = v.z; tile[kk][nc + 3] = v.w;
    }
    __syncthreads();
    int nn = t >> 2;
    int kk0 = (t & 3) * 16;
    u16 hs[16], ls[16];
    #pragma unroll
    for (int j = 0; j < 16; ++j) split1(tile[kk0 + j][nn], hs[j], ls[j]);
    size_t ob = (size_t)(bn + nn) * Kp + bk + kk0;
    size_t lo = (size_t)Np * Kp;
    *(short8*)&Wt[ob] = *(short8*)hs;
    *(short8*)&Wt[ob + 8] = *(short8*)&hs[8];
    *(short8*)&Wt[lo + ob] = *(short8*)ls;
    *(short8*)&Wt[lo + ob + 8] = *(short8*)&ls[8];
}

__device__ void xsplit_dev(const float* __restrict__ x, u16* __restrict__ xs, int gblk) {
    int t = threadIdx.x;
    int r0 = gblk * 16 + (t >> 4);
    int l = t & 15;
    u16* xlo = xs + (size_t)MP * 512;
    #pragma unroll
    for (int j = 0; j < 8; ++j) {
        int k = (l + j * 16) * 4;
        float vals[4] = {0.f, 0.f, 0.f, 0.f};
        if (r0 < NN && k < 500) {
            float4 v = *(const float4*)&x[(size_t)r0 * 500 + k];
            vals[0] = v.x; vals[1] = v.y; vals[2] = v.z; vals[3] = v.w;
        }
        ushort4 hs, ls;
        split1(vals[0], hs.x, ls.x); split1(vals[1], hs.y, ls.y);
        split1(vals[2], hs.z, ls.z); split1(vals[3], hs.w, ls.w);
        *(ushort4*)&xs[(size_t)r0 * 512 + k] = hs;
        *(ushort4*)&xlo[(size_t)r0 * 512 + k] = ls;
    }
}

// ---------------- scatter + xsplit + weight splits (one dispatch) ----------------
// [0,1290): edges+diag scatter; [1290,1922): xsplit; [1922,1954): W0; [1954,1956): fW1
__global__ __launch_bounds__(256)
void scatter_prep(const int* __restrict__ ei, unsigned int* __restrict__ bitmap,
                  const float* __restrict__ x,
                  const float* __restrict__ W0, const float* __restrict__ fW1,
                  u16* __restrict__ xs, u16* __restrict__ W0t, u16* __restrict__ fW1t) {
    __shared__ char smem[16704];
    int b = blockIdx.x;
    if (b < 1290) {
        int e = b * 256 + threadIdx.x;
        if (e < NE + NN) {
            int i, j;
            if (e < NE) { i = ei[e]; j = ei[NE + e]; }
            else        { i = e - NE; j = i; }
            atomicOr(&bitmap[i * ROW_WORDS + (j >> 5)], 1u << (j & 31));
        }
    } else if (b < 1922) {
        xsplit_dev(x, xs, b - 1290);
    } else if (b < 1954) {
        int idx = b - 1922;
        splitW_dev(W0, 500, 256, 512, 256, W0t, idx & 7, idx >> 3, smem);
    } else {
        splitW_dev(fW1, 128, 40, 128, 64, fW1t, b - 1954, 0, smem);
    }
}

// ---------------- conv0 GEMM (r11 form + in-prologue degree popcount) ----------
// H1 = deg ⊙ relu(deg*(x@W0) + b0); stats over relu output.
// Degree for this block's 64 rows computed from bitmap in the prologue (needed
// only in epilogue -> latency fully hidden by K-loop). bx==0 writes deg[] for conv1.
__global__ __launch_bounds__(256, 4)
void conv0_gemm(const u16* __restrict__ Ahi, const u16* __restrict__ Alo,
                const u16* __restrict__ Bhi, const u16* __restrict__ Blo,
                const unsigned int* __restrict__ bitmap, const float* __restrict__ bias,
                float* __restrict__ deg, float* __restrict__ stats,
                u16* __restrict__ Ohi, u16* __restrict__ Olo) {
    __shared__ char smem[32768];   // Ahi|Alo|Bhi|Blo, 8 KB each
    __shared__ float sdeg[64];
    const int Kp = 512, M = NN, No = 256;
    const int b = blockIdx.x;
    const int xcd = b & 7, g = b >> 3;
    const int bx = g & 3, by = (g >> 2) * 8 + xcd;
    if (by >= 158) return;
    const int t = threadIdx.x;
    const int lane = t & 63;
    const int w = t >> 6;
    const int q = lane >> 4;
    const int l16 = lane & 15;
    const int m7 = l16 & 7;
    const int row0 = by * 64;
    const int col0 = bx * 64;

    const u16* bases[4] = {Ahi, Alo, Bhi, Blo};
    const u16* srcs[8];
    unsigned dstoff[8];
    #pragma unroll
    for (int i = 0; i < 8; ++i) {
        int gi = w + i * 4;
        int reg = i >> 1;
        int j = gi & 7;
        int rb = (reg < 2) ? row0 : col0;
        int r = j * 8 + (lane >> 3);
        int c = (lane & 7) ^ (r & 7);
        srcs[i] = bases[reg] + (size_t)(rb + r) * Kp + c * 8;
        dstoff[i] = reg * 8192 + j * 1024;
    }

    f32x4 acc[4];
    #pragma unroll
    for (int s = 0; s < 4; ++s) acc[s] = (f32x4){0.f, 0.f, 0.f, 0.f};

    #pragma unroll
    for (int i = 0; i < 8; ++i) { gll16(srcs[i], smem + dstoff[i]); srcs[i] += 64; }

    // degree prologue: 4 threads/row popcount 320 words; result used in epilogue
    {
        int rr = t >> 2, wl = t & 3;
        int grow = row0 + rr;
        int cnt = 0;
        if (grow < NN)
            for (int wd = wl; wd < ROW_WORDS; wd += 4)
                cnt += __popc(bitmap[(size_t)grow * ROW_WORDS + wd]);
        cnt += __shfl_down(cnt, 1, 4);
        cnt += __shfl_down(cnt, 2, 4);
        if (wl == 0) {
            sdeg[rr] = (float)cnt;
            if (bx == 0 && grow < NN) deg[grow] = (float)cnt;
        }
    }

    for (int k0 = 0; k0 < Kp; k0 += 64) {
        __syncthreads();
        short8 ah[2], al[2], bh[2][4], bl[2][4];
        #pragma unroll
        for (int kc = 0; kc < 2; ++kc) {
            int aoff = (w * 16 + l16) * 128 + (((kc * 4 + q) ^ m7) * 16);
            ah[kc] = *(const short8*)(smem + aoff);
            al[kc] = *(const short8*)(smem + 8192 + aoff);
            #pragma unroll
            for (int s = 0; s < 4; ++s) {
                int boff = (s * 16 + l16) * 128 + (((kc * 4 + q) ^ m7) * 16);
                bh[kc][s] = *(const short8*)(smem + 16384 + boff);
                bl[kc][s] = *(const short8*)(smem + 24576 + boff);
            }
        }
        __syncthreads();
        if (k0 + 64 < Kp) {
            #pragma unroll
            for (int i = 0; i < 8; ++i) { gll16(srcs[i], smem + dstoff[i]); srcs[i] += 64; }
        }
        #pragma unroll
        for (int kc = 0; kc < 2; ++kc)
            #pragma unroll
            for (int s = 0; s < 4; ++s) {
                acc[s] = __builtin_amdgcn_mfma_f32_16x16x32_bf16(al[kc], bh[kc][s], acc[s], 0, 0, 0);
                acc[s] = __builtin_amdgcn_mfma_f32_16x16x32_bf16(ah[kc], bl[kc][s], acc[s], 0, 0, 0);
                acc[s] = __builtin_amdgcn_mfma_f32_16x16x32_bf16(ah[kc], bh[kc][s], acc[s], 0, 0, 0);
            }
    }

    int growb = row0 + w * 16 + q * 4;
    float dgv[4];
    #pragma unroll
    for (int r = 0; r < 4; ++r) {
        int grow = growb + r;
        dgv[r] = (grow < M) ? sdeg[grow - row0] : 0.f;
    }
    #pragma unroll
    for (int s = 0; s < 4; ++s) {
        int gc = col0 + s * 16 + l16;
        float bia = bias[gc];
        float s_sum = 0.f, ss_sum = 0.f;
        #pragma unroll
        for (int r = 0; r < 4; ++r) {
            int grow = growb + r;
            bool real = grow < M;
            float v = fmaxf(fmaf(dgv[r], acc[s][r], bia), 0.f);
            if (!real) v = 0.f;
            s_sum += v; ss_sum += v * v;
            float vo = v * dgv[r];
            u16 h, l; split1(vo, h, l);
            Ohi[(size_t)grow * No + gc] = h;
            Olo[(size_t)grow * No + gc] = l;
        }
        s_sum  += __shfl_xor(s_sum, 16);  s_sum  += __shfl_xor(s_sum, 32);
        ss_sum += __shfl_xor(ss_sum, 16); ss_sum += __shfl_xor(ss_sum, 32);
        if (lane < 16) {
            atomicAdd(&stats[gc], s_sum);
            atomicAdd(&stats[256 + gc], ss_sum);
        }
    }
}

// ---------------- conv1 with in-kernel BN0 fold of W1 (proven r11) ----------------
__global__ __launch_bounds__(256, 4)
void conv1_fold(const u16* __restrict__ Ahi, const u16* __restrict__ Alo,
                const float* __restrict__ W1, const float* __restrict__ stats0,
                const float* __restrict__ g0, const float* __restrict__ bb0,
                const float* __restrict__ b1, const float* __restrict__ deg,
                float* __restrict__ stats1, u16* __restrict__ Ohi, u16* __restrict__ Olo) {
    __shared__ char smem[32768];
    __shared__ float scl[256], sh[256], cred[256], cvec[64];
    const int Kp = 256, M = NN, No = 256;
    const int b = blockIdx.x;
    const int xcd = b & 7, g = b >> 3;
    const int bx = g & 3, by = (g >> 2) * 8 + xcd;
    if (by >= 158) return;
    const int t = threadIdx.x;
    const int lane = t & 63;
    const int w = t >> 6;
    const int q = lane >> 4;
    const int l16 = lane & 15;
    const int m7 = l16 & 7;
    const int row0 = by * 64;
    const int col0 = bx * 64;

    const u16* srcs[4];
    unsigned dstoff[4];
    #pragma unroll
    for (int i = 0; i < 4; ++i) {
        int gi = w + i * 4;
        int plane = gi >> 3, j = gi & 7;
        int r = j * 8 + (lane >> 3);
        int c = (lane & 7) ^ (r & 7);
        srcs[i] = (plane ? Alo : Ahi) + (size_t)(row0 + r) * Kp + c * 8;
        dstoff[i] = plane * 8192 + j * 1024;
    }
    #pragma unroll
    for (int i = 0; i < 4; ++i) { gll16(srcs[i], smem + dstoff[i]); srcs[i] += 64; }

    {
        float mean = stats0[t] * (1.f / NN);
        float var = stats0[256 + t] * (1.f / NN) - mean * mean;
        float s = g0[t] * rsqrtf(var + BN_EPS);
        scl[t] = s;
        sh[t] = bb0[t] - mean * s;
    }
    __syncthreads();
    {
        float s = 0.f;
        int n = col0 + (t & 63);
        #pragma unroll 8
        for (int k = (t >> 6); k < 256; k += 4)
            s += sh[k] * W1[(size_t)k * 256 + n];
        cred[t] = s;
        __syncthreads();
        if (t < 64) cvec[t] = cred[t] + cred[t + 64] + cred[t + 128] + cred[t + 192];
    }
    const int bn = t & 63;
    const int kb = (t >> 6) * 16;
    const int ch0 = (t >> 6) * 2;
    float vals[16];
    {
        const float* wp = W1 + (size_t)kb * 256 + col0 + bn;
        #pragma unroll
        for (int i = 0; i < 16; ++i) vals[i] = wp[(size_t)i * 256] * scl[kb + i];
    }

    f32x4 acc[4];
    #pragma unroll
    for (int s = 0; s < 4; ++s) acc[s] = (f32x4){0.f, 0.f, 0.f, 0.f};

    for (int k0 = 0; k0 < Kp; k0 += 64) {
        {
            u16 hs[16], ls[16];
            #pragma unroll
            for (int i = 0; i < 16; ++i) split1(vals[i], hs[i], ls[i]);
            unsigned o0 = bn * 128 + ((ch0 ^ (bn & 7)) * 16);
            unsigned o1 = bn * 128 + (((ch0 + 1) ^ (bn & 7)) * 16);
            *(short8*)(smem + 16384 + o0) = *(short8*)&hs[0];
            *(short8*)(smem + 16384 + o1) = *(short8*)&hs[8];
            *(short8*)(smem + 24576 + o0) = *(short8*)&ls[0];
            *(short8*)(smem + 24576 + o1) = *(short8*)&ls[8];
        }
        __syncthreads();   // (1)
        short8 ah[2], al[2], bh[2][4], bl[2][4];
        #pragma unroll
        for (int kc = 0; kc < 2; ++kc) {
            int aoff = (w * 16 + l16) * 128 + (((kc * 4 + q) ^ m7) * 16);
            ah[kc] = *(const short8*)(smem + aoff);
            al[kc] = *(const short8*)(smem + 8192 + aoff);
            #pragma unroll
            for (int s = 0; s < 4; ++s) {
                int boff = (s * 16 + l16) * 128 + (((kc * 4 + q) ^ m7) * 16);
                bh[kc][s] = *(const short8*)(smem + 16384 + boff);
                bl[kc][s] = *(const short8*)(smem + 24576 + boff);
            }
        }
        __syncthreads();   // (2)
        if (k0 + 64 < Kp) {
            #pragma unroll
            for (int i = 0; i < 4; ++i) { gll16(srcs[i], smem + dstoff[i]); srcs[i] += 64; }
            const float* wp = W1 + (size_t)(k0 + 64 + kb) * 256 + col0 + bn;
            #pragma unroll
            for (int i = 0; i < 16; ++i) vals[i] = wp[(size_t)i * 256] * scl[k0 + 64 + kb + i];
        }
        #pragma unroll
        for (int kc = 0; kc < 2; ++kc)
            #pragma unroll
            for (int s = 0; s < 4; ++s) {
                acc[s] = __builtin_amdgcn_mfma_f32_16x16x32_bf16(al[kc], bh[kc][s], acc[s], 0, 0, 0);
                acc[s] = __builtin_amdgcn_mfma_f32_16x16x32_bf16(ah[kc], bl[kc][s], acc[s], 0, 0, 0);
                acc[s] = __builtin_amdgcn_mfma_f32_16x16x32_bf16(ah[kc], bh[kc][s], acc[s], 0, 0, 0);
            }
    }

    int growb = row0 + w * 16 + q * 4;
    float dgv[4];
    #pragma unroll
    for (int r = 0; r < 4; ++r) dgv[r] = (growb + r < M) ? deg[growb + r] : 0.f;
    #pragma unroll
    for (int s = 0; s < 4; ++s) {
        int gc = col0 + s * 16 + l16;
        float bia = b1[gc];
        float cv = cvec[s * 16 + l16];
        float s_sum = 0.f, ss_sum = 0.f;
        #pragma unroll
        for (int r = 0; r < 4; ++r) {
            int grow = growb + r;
            bool real = grow < M;
            float v = fmaxf(fmaf(dgv[r], cv, acc[s][r] + bia), 0.f);
            if (!real) v = 0.f;
            s_sum += v; ss_sum += v * v;
            u16 h, l; split1(v, h, l);
            Ohi[(size_t)grow * No + gc] = h;
            Olo[(size_t)grow * No + gc] = l;
        }
        s_sum  += __shfl_xor(s_sum, 16);  s_sum  += __shfl_xor(s_sum, 32);
        ss_sum += __shfl_xor(ss_sum, 16); ss_sum += __shfl_xor(ss_sum, 32);
        if (lane < 16) {
            atomicAdd(&stats1[gc], s_sum);
            atomicAdd(&stats1[256 + gc], ss_sum);
        }
    }
}

// ---------------- fc0 with in-kernel BN1 fold of fW0 (proven r11) ----------------
__global__ __launch_bounds__(256, 4)
void fc0_fold(const u16* __restrict__ Ahi, const u16* __restrict__ Alo,
              const float* __restrict__ fW0, const float* __restrict__ stats1,
              const float* __restrict__ g1, const float* __restrict__ bb1,
              const float* __restrict__ fb0,
              u16* __restrict__ Ohi, u16* __restrict__ Olo) {
    __shared__ char smem[32768];
    __shared__ float scl[256], sh[256], cred[256], biasf[64];
    const int Kp = 256, M = NN, No = 128;
    const int b = blockIdx.x;
    const int xcd = b & 7, g = b >> 3;
    const int bx = g & 1, by = (g >> 1) * 8 + xcd;
    if (by >= 158) return;
    const int t = threadIdx.x;
    const int lane = t & 63;
    const int w = t >> 6;
    const int q = lane >> 4;
    const int l16 = lane & 15;
    const int m7 = l16 & 7;
    const int row0 = by * 64;
    const int col0 = bx * 64;

    const u16* srcs[4];
    unsigned dstoff[4];
    #pragma unroll
    for (int i = 0; i < 4; ++i) {
        int gi = w + i * 4;
        int plane = gi >> 3, j = gi & 7;
        int r = j * 8 + (lane >> 3);
        int c = (lane & 7) ^ (r & 7);
        srcs[i] = (plane ? Alo : Ahi) + (size_t)(row0 + r) * Kp + c * 8;
        dstoff[i] = plane * 8192 + j * 1024;
    }
    #pragma unroll
    for (int i = 0; i < 4; ++i) { gll16(srcs[i], smem + dstoff[i]); srcs[i] += 64; }

    {
        float mean = stats1[t] * (1.f / NN);
        float var = stats1[256 + t] * (1.f / NN) - mean * mean;
        float s = g1[t] * rsqrtf(var + BN_EPS);
        scl[t] = s;
        sh[t] = bb1[t] - mean * s;
    }
    __syncthreads();
    {
        float s = 0.f;
        int n = col0 + (t & 63);
        #pragma unroll 8
        for (int k = (t >> 6); k < 256; k += 4)
            s += sh[k] * fW0[(size_t)k * 128 + n];
        cred[t] = s;
        __syncthreads();
        if (t < 64)
            biasf[t] = fb0[col0 + t] + cred[t] + cred[t + 64] + cred[t + 128] + cred[t + 192];
    }
    const int bn = t & 63;
    const int kb = (t >> 6) * 16;
    const int ch0 = (t >> 6) * 2;
    float vals[16];
    {
        const float* wp = fW0 + (size_t)kb * 128 + col0 + bn;
        #pragma unroll
        for (int i = 0; i < 16; ++i) vals[i] = wp[(size_t)i * 128] * scl[kb + i];
    }

    f32x4 acc[4];
    #pragma unroll
    for (int s = 0; s < 4; ++s) acc[s] = (f32x4){0.f, 0.f, 0.f, 0.f};

    for (int k0 = 0; k0 < Kp; k0 += 64) {
        {
            u16 hs[16], ls[16];
            #pragma unroll
            for (int i = 0; i < 16; ++i) split1(vals[i], hs[i], ls[i]);
            unsigned o0 = bn * 128 + ((ch0 ^ (bn & 7)) * 16);
            unsigned o1 = bn * 128 + (((ch0 + 1) ^ (bn & 7)) * 16);
            *(short8*)(smem + 16384 + o0) = *(short8*)&hs[0];
            *(short8*)(smem + 16384 + o1) = *(short8*)&hs[8];
            *(short8*)(smem + 24576 + o0) = *(short8*)&ls[0];
            *(short8*)(smem + 24576 + o1) = *(short8*)&ls[8];
        }
        __syncthreads();   // (1)
        short8 ah[2], al[2], bh[2][4], bl[2][4];
        #pragma unroll
        for (int kc = 0; kc < 2; ++kc) {
            int aoff = (w * 16 + l16) * 128 + (((kc * 4 + q) ^ m7) * 16);
            ah[kc] = *(const short8*)(smem + aoff);
            al[kc] = *(const short8*)(smem + 8192 + aoff);
            #pragma unroll
            for (int s = 0; s < 4; ++s) {
                int boff = (s * 16 + l16) * 128 + (((kc * 4 + q) ^ m7) * 16);
                bh[kc][s] = *(const short8*)(smem + 16384 + boff);
                bl[kc][s] = *(const short8*)(smem + 24576 + boff);
            }
        }
        __syncthreads();   // (2)
        if (k0 + 64 < Kp) {
            #pragma unroll
            for (int i = 0; i < 4; ++i) { gll16(srcs[i], smem + dstoff[i]); srcs[i] += 64; }
            const float* wp = fW0 + (size_t)(k0 + 64 + kb) * 128 + col0 + bn;
            #pragma unroll
            for (int i = 0; i < 16; ++i) vals[i] = wp[(size_t)i * 128] * scl[k0 + 64 + kb + i];
        }
        #pragma unroll
        for (int kc = 0; kc < 2; ++kc)
            #pragma unroll
            for (int s = 0; s < 4; ++s) {
                acc[s] = __builtin_amdgcn_mfma_f32_16x16x32_bf16(al[kc], bh[kc][s], acc[s], 0, 0, 0);
                acc[s] = __builtin_amdgcn_mfma_f32_16x16x32_bf16(ah[kc], bl[kc][s], acc[s], 0, 0, 0);
                acc[s] = __builtin_amdgcn_mfma_f32_16x16x32_bf16(ah[kc], bh[kc][s], acc[s], 0, 0, 0);
            }
    }

    int growb = row0 + w * 16 + q * 4;
    #pragma unroll
    for (int s = 0; s < 4; ++s) {
        int gc = col0 + s * 16 + l16;
        float bia = biasf[s * 16 + l16];
        #pragma unroll
        for (int r = 0; r < 4; ++r) {
            int grow = growb + r;
            float v = fmaxf(acc[s][r] + bia, 0.f);
            if (grow >= M) v = 0.f;
            u16 h, l; split1(v, h, l);
            Ohi[(size_t)grow * No + gc] = h;
            Olo[(size_t)grow * No + gc] = l;
        }
    }
}

// ---------------- fc1 (proven): Kp=128, N=40, fp32 out ----------------
__global__ __launch_bounds__(256, 3)
void fc1_gemm(const u16* __restrict__ Ahi, const u16* __restrict__ Alo,
              const u16* __restrict__ Bhi, const u16* __restrict__ Blo,
              const float* __restrict__ bias, float* __restrict__ out) {
    __shared__ char smem[32768];
    const int Kp = 128, M = NN, N = 40, No = 40;
    const int t = threadIdx.x;
    const int lane = t & 63;
    const int w = t >> 6;
    const int q = lane >> 4;
    const int l16 = lane & 15;
    const int m7 = l16 & 7;
    const int row0 = blockIdx.x * 64;
    const int col0 = 0;

    const u16* bases[4] = {Ahi, Alo, Bhi, Blo};
    const u16* srcs[8];
    unsigned dstoff[8];
    #pragma unroll
    for (int i = 0; i < 8; ++i) {
        int gi = w + i * 4;
        int reg = i >> 1;
        int j = gi & 7;
        int rb = (reg < 2) ? row0 : col0;
        int r = j * 8 + (lane >> 3);
        int c = (lane & 7) ^ (r & 7);
        srcs[i] = bases[reg] + (size_t)(rb + r) * Kp + c * 8;
        dstoff[i] = reg * 8192 + j * 1024;
    }

    f32x4 acc[4];
    #pragma unroll
    for (int s = 0; s < 4; ++s) acc[s] = (f32x4){0.f, 0.f, 0.f, 0.f};

    #pragma unroll
    for (int i = 0; i < 8; ++i) { gll16(srcs[i], smem + dstoff[i]); srcs[i] += 64; }

    for (int k0 = 0; k0 < Kp; k0 += 64) {
        __syncthreads();
        short8 ah[2], al[2], bh[2][4], bl[2][4];
        #pragma unroll
        for (int kc = 0; kc < 2; ++kc) {
            int aoff = (w * 16 + l16) * 128 + (((kc * 4 + q) ^ m7) * 16);
            ah[kc] = *(const short8*)(smem + aoff);
            al[kc] = *(const short8*)(smem + 8192 + aoff);
            #pragma unroll
            for (int s = 0; s < 4; ++s) {
                int boff = (s * 16 + l16) * 128 + (((kc * 4 + q) ^ m7) * 16);
                bh[kc][s] = *(const short8*)(smem + 16384 + boff);
                bl[kc][s] = *(const short8*)(smem + 24576 + boff);
            }
        }
        __syncthreads();
        if (k0 + 64 < Kp) {
            #pragma unroll
            for (int i = 0; i < 8; ++i) { gll16(srcs[i], smem + dstoff[i]); srcs[i] += 64; }
        }
        #pragma unroll
        for (int kc = 0; kc < 2; ++kc)
            #pragma unroll
            for (int s = 0; s < 4; ++s) {
                acc[s] = __builtin_amdgcn_mfma_f32_16x16x32_bf16(al[kc], bh[kc][s], acc[s], 0, 0, 0);
                acc[s] = __builtin_amdgcn_mfma_f32_16x16x32_bf16(ah[kc], bl[kc][s], acc[s], 0, 0, 0);
                acc[s] = __builtin_amdgcn_mfma_f32_16x16x32_bf16(ah[kc], bh[kc][s], acc[s], 0, 0, 0);
            }
    }

    int growb = row0 + w * 16 + q * 4;
    #pragma unroll
    for (int s = 0; s < 4; ++s) {
        int gc = col0 + s * 16 + l16;
        if (gc >= N) continue;
        float bia = bias[gc];
        #pragma unroll
        for (int r = 0; r < 4; ++r) {
            int grow = growb + r;
            if (grow < M)
                out[(size_t)grow * No + gc] = fmaxf(acc[s][r] + bia, 0.f);
        }
    }
}

// ---------------- launch ----------------

extern "C" void kernel_launch(void* const* d_in, const int* in_sizes, int n_in,
                              void* d_out, int out_size, void* d_ws, size_t ws_size,
                              hipStream_t stream) {
    const float* x   = (const float*)d_in[0];
    const int*   ei  = (const int*)d_in[1];
    const float* W0  = (const float*)d_in[2];
    const float* b0  = (const float*)d_in[3];
    const float* g0  = (const float*)d_in[4];
    const float* bb0 = (const float*)d_in[5];
    const float* W1  = (const float*)d_in[6];
    const float* b1  = (const float*)d_in[7];
    const float* g1  = (const float*)d_in[8];
    const float* bb1 = (const float*)d_in[9];
    const float* fW0 = (const float*)d_in[10];
    const float* fb0 = (const float*)d_in[11];
    const float* fW1 = (const float*)d_in[12];
    const float* fb1 = (const float*)d_in[13];
    float* out = (float*)d_out;

    char* ws = (char*)d_ws;
    auto carve = [&](size_t bytes) { char* q = ws; ws += (bytes + 255) & ~(size_t)255; return q; };

    const size_t BITMAP_BYTES = (size_t)NN * ROW_WORDS * 4;   // 12,800,000
    char* region0 = carve(BITMAP_BYTES + 4096);
    unsigned int* bitmap = (unsigned int*)region0;
    float* stats = (float*)(region0 + BITMAP_BYTES);   // [0,512) conv0, [512,1024) conv1

    float* deg  = (float*)carve(MP * 4);
    u16* xs     = (u16*)carve((size_t)2 * MP * 512 * 2);
    u16* W0t    = (u16*)carve((size_t)2 * 256 * 512 * 2);
    u16* fW1t   = (u16*)carve((size_t)2 * 64 * 128 * 2);
    u16* H1     = (u16*)carve((size_t)2 * MP * 256 * 2);   // NOT aliased with bitmap
    u16* H2     = (u16*)carve((size_t)2 * MP * 256 * 2);
    u16* H3     = (u16*)carve((size_t)2 * MP * 128 * 2);

    dim3 blk(256);

    // 1. zero bitmap + stats
    hipMemsetAsync(region0, 0, BITMAP_BYTES + 4096, stream);
    // 2. scatter edges + split x + split W0/fW1 (one dispatch)
    scatter_prep<<<1956, blk, 0, stream>>>(ei, bitmap, x, W0, fW1, xs, W0t, fW1t);
    // 3. conv0 (degree computed in prologue from bitmap; deg written for conv1)
    conv0_gemm<<<640, blk, 0, stream>>>(
        xs, xs + (size_t)MP * 512, W0t, W0t + 256 * 512,
        bitmap, b0, deg, stats, H1, H1 + (size_t)MP * 256);
    // 4. conv1 (self-folds BN0 into W1; swizzled)
    conv1_fold<<<640, blk, 0, stream>>>(
        H1, H1 + (size_t)MP * 256, W1, stats, g0, bb0, b1, deg,
        stats + 512, H2, H2 + (size_t)MP * 256);
    // 5. fc0 (self-folds BN1 into fW0; swizzled)
    fc0_fold<<<320, blk, 0, stream>>>(
        H2, H2 + (size_t)MP * 256, fW0, stats + 512, g1, bb1, fb0,
        H3, H3 + (size_t)MP * 128);
    // 6. fc1
    fc1_gemm<<<158, blk, 0, stream>>>(
        H3, H3 + (size_t)MP * 128, fW1t, fW1t + 64 * 128, fb1, out);
}